// Round 1
// baseline (807.220 us; speedup 1.0000x reference)
//
#include <hip/hip_runtime.h>
#include <stdint.h>

#define TS 524288u
#define TMASK (TS - 1u)

__global__ __launch_bounds__(256)
void ngp_fused(const float* __restrict__ xg, const float* __restrict__ dg,
               const float* __restrict__ tables,
               const float* __restrict__ dW1, const float* __restrict__ db1,
               const float* __restrict__ dW2, const float* __restrict__ db2,
               const float* __restrict__ cW1, const float* __restrict__ cb1,
               const float* __restrict__ cW2, const float* __restrict__ cb2,
               const float* __restrict__ cW3, const float* __restrict__ cb3,
               float* __restrict__ out, int n)
{
    const int tid = blockIdx.x * blockDim.x + threadIdx.x;
    if (tid >= n) return;

    const float px = xg[3*tid+0], py = xg[3*tid+1], pz = xg[3*tid+2];
    float sx = px / 3.0f, sy = py / 3.0f, sz = pz / 3.0f;
    const bool inside = (fabsf(sx) < 0.5f) && (fabsf(sy) < 0.5f) && (fabsf(sz) < 0.5f);
    if (!inside) {
        // reference: color=0, log_sigma=-10000 -> sigma=exp(-10000)=0
        out[3*tid+0] = 0.0f; out[3*tid+1] = 0.0f; out[3*tid+2] = 0.0f;
        out[(size_t)3*n + tid] = 0.0f;
        return;
    }
    sx = fminf(fmaxf(sx + 0.5f, 0.0f), 1.0f);
    sy = fminf(fmaxf(sy + 0.5f, 0.0f), 1.0f);
    sz = fminf(fmaxf(sz + 0.5f, 0.0f), 1.0f);

    // ---------------- multi-resolution hash encode ----------------
    float feats[32];
    constexpr int NLv[16] = {16,22,30,42,58,80,111,153,212,293,406,561,775,1071,1481,2046};
    #pragma unroll
    for (int i = 0; i < 16; ++i) {
        const float nf = (float)NLv[i];
        const float xn0 = sx * nf, xn1 = sy * nf, xn2 = sz * nf;
        const float fl0 = floorf(xn0), fl1 = floorf(xn1), fl2 = floorf(xn2);
        const float w0 = xn0 - fl0, w1 = xn1 - fl1, w2 = xn2 - fl2;
        const uint32_t f0 = (uint32_t)fl0, f1 = (uint32_t)fl1, f2 = (uint32_t)fl2;
        const uint32_t c0 = (uint32_t)ceilf(xn0), c1 = (uint32_t)ceilf(xn1), c2 = (uint32_t)ceilf(xn2);
        const float* tb = tables + (size_t)i * (size_t)(TS * 2u);
        float a0 = 0.0f, a1 = 0.0f;
        #pragma unroll
        for (int v = 0; v < 8; ++v) {
            const uint32_t hx = (v & 1) ? c0 : f0;
            const uint32_t hy = (v & 2) ? c1 : f1;
            const uint32_t hz = (v & 4) ? c2 : f2;
            const uint32_t hh = (hx ^ (hy * 2654435761u) ^ (hz * 805459861u)) & TMASK;
            const float2 val = *reinterpret_cast<const float2*>(tb + (size_t)(2u * hh));
            const float wc = ((v & 1) ? w0 : 1.0f - w0)
                           * ((v & 2) ? w1 : 1.0f - w1)
                           * ((v & 4) ? w2 : 1.0f - w2);
            a0 = fmaf(wc, val.x, a0);
            a1 = fmaf(wc, val.y, a1);
        }
        feats[2*i+0] = a0;
        feats[2*i+1] = a1;
    }

    // ---------------- density MLP: 32 -> 64 (relu) -> 16 ----------------
    float hid[64];
    #pragma unroll
    for (int j = 0; j < 64; ++j) hid[j] = db1[j];
    #pragma unroll
    for (int k = 0; k < 32; ++k) {
        const float xv = feats[k];
        #pragma unroll
        for (int j = 0; j < 64; ++j) hid[j] = fmaf(xv, dW1[k*64+j], hid[j]);
    }
    #pragma unroll
    for (int j = 0; j < 64; ++j) hid[j] = fmaxf(hid[j], 0.0f);

    float h16[16];
    #pragma unroll
    for (int j = 0; j < 16; ++j) h16[j] = db2[j];
    #pragma unroll
    for (int k = 0; k < 64; ++k) {
        const float xv = hid[k];
        #pragma unroll
        for (int j = 0; j < 16; ++j) h16[j] = fmaf(xv, dW2[k*16+j], h16[j]);
    }

    // sigma out (mask is true here)
    out[(size_t)3*n + tid] = __expf(h16[0]);

    // ---------------- color input: [h16 (16), pos_enc(d) (27)] ----------------
    const float dx = dg[3*tid+0], dy = dg[3*tid+1], dz = dg[3*tid+2];
    float cin[43];
    #pragma unroll
    for (int j = 0; j < 16; ++j) cin[j] = h16[j];
    cin[16] = dx; cin[17] = dy; cin[18] = dz;
    #pragma unroll
    for (int f = 0; f < 4; ++f) {
        const float s = (float)(1 << f);
        cin[19 + 6*f + 0] = __sinf(s * dx);
        cin[19 + 6*f + 1] = __sinf(s * dy);
        cin[19 + 6*f + 2] = __sinf(s * dz);
        cin[22 + 6*f + 0] = __cosf(s * dx);
        cin[22 + 6*f + 1] = __cosf(s * dy);
        cin[22 + 6*f + 2] = __cosf(s * dz);
    }

    // ---------------- color MLP: 43 -> 64 (relu) -> 64 (relu) -> 3 (sigmoid) ----------------
    float c1[64];
    #pragma unroll
    for (int j = 0; j < 64; ++j) c1[j] = cb1[j];
    #pragma unroll
    for (int k = 0; k < 43; ++k) {
        const float xv = cin[k];
        #pragma unroll
        for (int j = 0; j < 64; ++j) c1[j] = fmaf(xv, cW1[k*64+j], c1[j]);
    }
    #pragma unroll
    for (int j = 0; j < 64; ++j) c1[j] = fmaxf(c1[j], 0.0f);

    float c2[64];
    #pragma unroll
    for (int j = 0; j < 64; ++j) c2[j] = cb2[j];
    #pragma unroll
    for (int k = 0; k < 64; ++k) {
        const float xv = c1[k];
        #pragma unroll
        for (int j = 0; j < 64; ++j) c2[j] = fmaf(xv, cW2[k*64+j], c2[j]);
    }
    #pragma unroll
    for (int j = 0; j < 64; ++j) c2[j] = fmaxf(c2[j], 0.0f);

    float c3[3];
    #pragma unroll
    for (int j = 0; j < 3; ++j) c3[j] = cb3[j];
    #pragma unroll
    for (int k = 0; k < 64; ++k) {
        const float xv = c2[k];
        #pragma unroll
        for (int j = 0; j < 3; ++j) c3[j] = fmaf(xv, cW3[k*3+j], c3[j]);
    }
    #pragma unroll
    for (int j = 0; j < 3; ++j) {
        const float z = c3[j];
        out[3*tid+j] = 1.0f / (1.0f + __expf(-z));
    }
}

extern "C" void kernel_launch(void* const* d_in, const int* in_sizes, int n_in,
                              void* d_out, int out_size, void* d_ws, size_t ws_size,
                              hipStream_t stream)
{
    const float* x   = (const float*)d_in[0];
    const float* d   = (const float*)d_in[1];
    const float* tb  = (const float*)d_in[2];
    const float* dW1 = (const float*)d_in[3];
    const float* db1 = (const float*)d_in[4];
    const float* dW2 = (const float*)d_in[5];
    const float* db2 = (const float*)d_in[6];
    const float* cW1 = (const float*)d_in[7];
    const float* cb1 = (const float*)d_in[8];
    const float* cW2 = (const float*)d_in[9];
    const float* cb2 = (const float*)d_in[10];
    const float* cW3 = (const float*)d_in[11];
    const float* cb3 = (const float*)d_in[12];
    float* out = (float*)d_out;

    const int n = in_sizes[0] / 3;  // N_PTS
    dim3 block(256);
    dim3 grid((n + 255) / 256);
    hipLaunchKernelGGL(ngp_fused, grid, block, 0, stream,
                       x, d, tb, dW1, db1, dW2, db2,
                       cW1, cb1, cW2, cb2, cW3, cb3, out, n);
}

// Round 2
// 803.657 us; speedup vs baseline: 1.0044x; 1.0044x over previous
//
#include <hip/hip_runtime.h>
#include <stdint.h>

#define TS 524288u
#define TMASK (TS - 1u)

// __launch_bounds__(256, 2): 2 waves/EU min -> 256-VGPR budget. With the
// default (no 2nd arg) the compiler targeted ~64 VGPRs (VGPR_Count=68 in R1)
// and serialized/recomputed the unrolled MLP arrays -> latency-bound at 700us.
__global__ __launch_bounds__(256, 2)
void ngp_fused(const float* __restrict__ xg, const float* __restrict__ dg,
               const float* __restrict__ tables,
               const float* __restrict__ dW1, const float* __restrict__ db1,
               const float* __restrict__ dW2, const float* __restrict__ db2,
               const float* __restrict__ cW1, const float* __restrict__ cb1,
               const float* __restrict__ cW2, const float* __restrict__ cb2,
               const float* __restrict__ cW3, const float* __restrict__ cb3,
               float* __restrict__ out, int n)
{
    const int tid = blockIdx.x * blockDim.x + threadIdx.x;
    if (tid >= n) return;

    const float px = xg[3*tid+0], py = xg[3*tid+1], pz = xg[3*tid+2];
    float sx = px / 3.0f, sy = py / 3.0f, sz = pz / 3.0f;
    const bool inside = (fabsf(sx) < 0.5f) && (fabsf(sy) < 0.5f) && (fabsf(sz) < 0.5f);
    if (!inside) {
        out[3*tid+0] = 0.0f; out[3*tid+1] = 0.0f; out[3*tid+2] = 0.0f;
        out[(size_t)3*n + tid] = 0.0f;   // exp(-10000) == 0
        return;
    }
    sx = fminf(fmaxf(sx + 0.5f, 0.0f), 1.0f);
    sy = fminf(fmaxf(sy + 0.5f, 0.0f), 1.0f);
    sz = fminf(fmaxf(sz + 0.5f, 0.0f), 1.0f);

    constexpr int NLv[16] = {16,22,30,42,58,80,111,153,212,293,406,561,775,1071,1481,2046};

    // ---------------- multi-resolution hash encode (2-stage pipelined) -------
    // Issue level i+1's 8 gathers before consuming level i's values so ~16
    // independent loads are in flight per wave.
    float feats[32];

    float w0, w1, w2;
    float2 v[8];

    // helper expanded manually: compute addresses + issue loads for level i
    #define LEVEL_ADDR_LOAD(LI, VDST, W0, W1, W2)                                     \
    {                                                                                  \
        const float nf = (float)NLv[LI];                                               \
        const float xn0 = sx * nf, xn1 = sy * nf, xn2 = sz * nf;                       \
        const float fl0 = floorf(xn0), fl1 = floorf(xn1), fl2 = floorf(xn2);           \
        W0 = xn0 - fl0; W1 = xn1 - fl1; W2 = xn2 - fl2;                                \
        const uint32_t f0 = (uint32_t)fl0, f1 = (uint32_t)fl1, f2 = (uint32_t)fl2;     \
        const uint32_t c0 = (uint32_t)ceilf(xn0), c1_ = (uint32_t)ceilf(xn1),          \
                       c2_ = (uint32_t)ceilf(xn2);                                     \
        const uint32_t hyf = f1 * 2654435761u, hyc = c1_ * 2654435761u;                \
        const uint32_t hzf = f2 * 805459861u,  hzc = c2_ * 805459861u;                 \
        const float* tb = tables + (size_t)(LI) * (size_t)(TS * 2u);                   \
        VDST[0] = *reinterpret_cast<const float2*>(tb + 2u*((f0 ^ hyf ^ hzf) & TMASK));\
        VDST[1] = *reinterpret_cast<const float2*>(tb + 2u*((c0 ^ hyf ^ hzf) & TMASK));\
        VDST[2] = *reinterpret_cast<const float2*>(tb + 2u*((f0 ^ hyc ^ hzf) & TMASK));\
        VDST[3] = *reinterpret_cast<const float2*>(tb + 2u*((c0 ^ hyc ^ hzf) & TMASK));\
        VDST[4] = *reinterpret_cast<const float2*>(tb + 2u*((f0 ^ hyf ^ hzc) & TMASK));\
        VDST[5] = *reinterpret_cast<const float2*>(tb + 2u*((c0 ^ hyf ^ hzc) & TMASK));\
        VDST[6] = *reinterpret_cast<const float2*>(tb + 2u*((f0 ^ hyc ^ hzc) & TMASK));\
        VDST[7] = *reinterpret_cast<const float2*>(tb + 2u*((c0 ^ hyc ^ hzc) & TMASK));\
    }

    LEVEL_ADDR_LOAD(0, v, w0, w1, w2)

    #pragma unroll
    for (int i = 0; i < 16; ++i) {
        float2 vn[8];
        float w0n = 0.f, w1n = 0.f, w2n = 0.f;
        if (i < 15) {
            switch (i + 1) {  // constant level index for each unrolled iteration
                case 1:  LEVEL_ADDR_LOAD(1,  vn, w0n, w1n, w2n) break;
                case 2:  LEVEL_ADDR_LOAD(2,  vn, w0n, w1n, w2n) break;
                case 3:  LEVEL_ADDR_LOAD(3,  vn, w0n, w1n, w2n) break;
                case 4:  LEVEL_ADDR_LOAD(4,  vn, w0n, w1n, w2n) break;
                case 5:  LEVEL_ADDR_LOAD(5,  vn, w0n, w1n, w2n) break;
                case 6:  LEVEL_ADDR_LOAD(6,  vn, w0n, w1n, w2n) break;
                case 7:  LEVEL_ADDR_LOAD(7,  vn, w0n, w1n, w2n) break;
                case 8:  LEVEL_ADDR_LOAD(8,  vn, w0n, w1n, w2n) break;
                case 9:  LEVEL_ADDR_LOAD(9,  vn, w0n, w1n, w2n) break;
                case 10: LEVEL_ADDR_LOAD(10, vn, w0n, w1n, w2n) break;
                case 11: LEVEL_ADDR_LOAD(11, vn, w0n, w1n, w2n) break;
                case 12: LEVEL_ADDR_LOAD(12, vn, w0n, w1n, w2n) break;
                case 13: LEVEL_ADDR_LOAD(13, vn, w0n, w1n, w2n) break;
                case 14: LEVEL_ADDR_LOAD(14, vn, w0n, w1n, w2n) break;
                case 15: LEVEL_ADDR_LOAD(15, vn, w0n, w1n, w2n) break;
            }
        }
        // consume level i
        const float u0 = 1.0f - w0, u1 = 1.0f - w1, u2 = 1.0f - w2;
        float a0, a1;
        a0 = u0*u1*u2 * v[0].x;                 a1 = u0*u1*u2 * v[0].y;
        a0 = fmaf(w0*u1*u2, v[1].x, a0);        a1 = fmaf(w0*u1*u2, v[1].y, a1);
        a0 = fmaf(u0*w1*u2, v[2].x, a0);        a1 = fmaf(u0*w1*u2, v[2].y, a1);
        a0 = fmaf(w0*w1*u2, v[3].x, a0);        a1 = fmaf(w0*w1*u2, v[3].y, a1);
        a0 = fmaf(u0*u1*w2, v[4].x, a0);        a1 = fmaf(u0*u1*w2, v[4].y, a1);
        a0 = fmaf(w0*u1*w2, v[5].x, a0);        a1 = fmaf(w0*u1*w2, v[5].y, a1);
        a0 = fmaf(u0*w1*w2, v[6].x, a0);        a1 = fmaf(u0*w1*w2, v[6].y, a1);
        a0 = fmaf(w0*w1*w2, v[7].x, a0);        a1 = fmaf(w0*w1*w2, v[7].y, a1);
        feats[2*i+0] = a0;
        feats[2*i+1] = a1;

        if (i < 15) {
            #pragma unroll
            for (int q = 0; q < 8; ++q) v[q] = vn[q];
            w0 = w0n; w1 = w1n; w2 = w2n;
        }
    }
    #undef LEVEL_ADDR_LOAD

    // ---------------- density MLP: 32 -> 64 (relu) -> 16 ----------------
    float hid[64];
    #pragma unroll
    for (int j = 0; j < 64; ++j) hid[j] = db1[j];
    #pragma unroll
    for (int k = 0; k < 32; ++k) {
        const float xv = feats[k];
        #pragma unroll
        for (int j = 0; j < 64; ++j) hid[j] = fmaf(xv, dW1[k*64+j], hid[j]);
    }
    #pragma unroll
    for (int j = 0; j < 64; ++j) hid[j] = fmaxf(hid[j], 0.0f);

    float h16[16];
    #pragma unroll
    for (int j = 0; j < 16; ++j) h16[j] = db2[j];
    #pragma unroll
    for (int k = 0; k < 64; ++k) {
        const float xv = hid[k];
        #pragma unroll
        for (int j = 0; j < 16; ++j) h16[j] = fmaf(xv, dW2[k*16+j], h16[j]);
    }

    out[(size_t)3*n + tid] = __expf(h16[0]);

    // ---------------- color input: [h16 (16), pos_enc(d) (27)] ----------------
    const float dx = dg[3*tid+0], dy = dg[3*tid+1], dz = dg[3*tid+2];
    float cin[43];
    #pragma unroll
    for (int j = 0; j < 16; ++j) cin[j] = h16[j];
    cin[16] = dx; cin[17] = dy; cin[18] = dz;
    #pragma unroll
    for (int f = 0; f < 4; ++f) {
        const float s = (float)(1 << f);
        cin[19 + 6*f + 0] = __sinf(s * dx);
        cin[19 + 6*f + 1] = __sinf(s * dy);
        cin[19 + 6*f + 2] = __sinf(s * dz);
        cin[22 + 6*f + 0] = __cosf(s * dx);
        cin[22 + 6*f + 1] = __cosf(s * dy);
        cin[22 + 6*f + 2] = __cosf(s * dz);
    }

    // ---------------- color MLP: 43 -> 64 (relu) -> 64 (relu) -> 3 (sigmoid) --
    float c1[64];
    #pragma unroll
    for (int j = 0; j < 64; ++j) c1[j] = cb1[j];
    #pragma unroll
    for (int k = 0; k < 43; ++k) {
        const float xv = cin[k];
        #pragma unroll
        for (int j = 0; j < 64; ++j) c1[j] = fmaf(xv, cW1[k*64+j], c1[j]);
    }
    #pragma unroll
    for (int j = 0; j < 64; ++j) c1[j] = fmaxf(c1[j], 0.0f);

    float c2[64];
    #pragma unroll
    for (int j = 0; j < 64; ++j) c2[j] = cb2[j];
    #pragma unroll
    for (int k = 0; k < 64; ++k) {
        const float xv = c1[k];
        #pragma unroll
        for (int j = 0; j < 64; ++j) c2[j] = fmaf(xv, cW2[k*64+j], c2[j]);
    }
    #pragma unroll
    for (int j = 0; j < 64; ++j) c2[j] = fmaxf(c2[j], 0.0f);

    float c3[3];
    #pragma unroll
    for (int j = 0; j < 3; ++j) c3[j] = cb3[j];
    #pragma unroll
    for (int k = 0; k < 64; ++k) {
        const float xv = c2[k];
        #pragma unroll
        for (int j = 0; j < 3; ++j) c3[j] = fmaf(xv, cW3[k*3+j], c3[j]);
    }
    #pragma unroll
    for (int j = 0; j < 3; ++j) {
        out[3*tid+j] = 1.0f / (1.0f + __expf(-c3[j]));
    }
}

extern "C" void kernel_launch(void* const* d_in, const int* in_sizes, int n_in,
                              void* d_out, int out_size, void* d_ws, size_t ws_size,
                              hipStream_t stream)
{
    const float* x   = (const float*)d_in[0];
    const float* d   = (const float*)d_in[1];
    const float* tb  = (const float*)d_in[2];
    const float* dW1 = (const float*)d_in[3];
    const float* db1 = (const float*)d_in[4];
    const float* dW2 = (const float*)d_in[5];
    const float* db2 = (const float*)d_in[6];
    const float* cW1 = (const float*)d_in[7];
    const float* cb1 = (const float*)d_in[8];
    const float* cW2 = (const float*)d_in[9];
    const float* cb2 = (const float*)d_in[10];
    const float* cW3 = (const float*)d_in[11];
    const float* cb3 = (const float*)d_in[12];
    float* out = (float*)d_out;

    const int n = in_sizes[0] / 3;  // N_PTS
    dim3 block(256);
    dim3 grid((n + 255) / 256);
    hipLaunchKernelGGL(ngp_fused, grid, block, 0, stream,
                       x, d, tb, dW1, db1, dW2, db2,
                       cW1, cb1, cW2, cb2, cW3, cb3, out, n);
}